// Round 9
// baseline (282.231 us; speedup 1.0000x reference)
//
#include <hip/hip_runtime.h>
#include <math.h>

#define H 1024
#define H3 3072
#define NVOC 256

typedef __attribute__((ext_vector_type(8))) short bf16x8;
typedef __attribute__((ext_vector_type(4))) float f32x4;

__device__ __forceinline__ float sigf(float x) { return 1.0f / (1.0f + expf(-x)); }

__device__ __forceinline__ unsigned short f2bf(float f) {
    unsigned int u = __float_as_uint(f);
    u = (u + 0x7fffu + ((u >> 16) & 1u)) >> 16;   // RNE
    return (unsigned short)u;
}
__device__ __forceinline__ float bf2f(unsigned short u) {
    return __uint_as_float(((unsigned int)u) << 16);
}

// ===== gemm_gru: K7+K8 fused. gh2 = h2 @ W_hh^T + b_hh, then GRU step-3 combine
// in-register -> clauseb. 256x(3x64)-gate-strided tile, 512 thr, BK=64, 8-phase.
// Grid 16x16 = 256 blocks = full chip. LDS 112 KiB: 2 bufs x (A[256][64] 32KB +
// B[192][64] 24KB); B rows = W_hh rows {g*1024 + h0 + 0..63, g=0,1,2}.
// 7 stage units/tile: u0-3 A, u4-6 B. Schedule (R7-proven choreography, 7 units):
//   ph1 RD(A-mh0,k0; B,k0) stage(t+1,u1) | ph2 RD(..,k1) stage(t+1,u3)
//   ph3 RD(A-mh1,k0)  stage(t+2,{u0,u2}) | ph4 RD(A-mh1,k1) stage(t+2,{u4,u5,u6})
//   vmcnt(5) once per tile at ph4 (= tile t+1 fully arrived; t+2's 5 in flight).
// Swizzle: 16B-slot = chunk ^ (row&7) on stage-source and ds_read (2-way residual).
__global__ __launch_bounds__(512, 2)
void gemm_gru(const unsigned short* __restrict__ A, const unsigned short* __restrict__ W,
              const float* __restrict__ bias, const float* __restrict__ Gi,
              const int* __restrict__ toks, unsigned short* __restrict__ outb,
              int K, int gx)
{
    __shared__ char ldsb[114688];
    const int tid = threadIdx.x;
    const int wid = tid >> 6, lane = tid & 63;

    // XCD-aware bijective swizzle (grid = 256, %8 == 0)
    const int nwg = gridDim.x;
    const int cpx = nwg >> 3;
    const int bid = blockIdx.x;
    const int swz = (bid & 7) * cpx + (bid >> 3);
    const int bm = (swz / gx) * 256;          // output row base
    const int hbase = (swz % gx) * 64;        // h-column group base

    const int gm = wid >> 2;                  // m-half of the wave (128 rows)
    const int hb = (wid & 3) * 16;            // h-subblock of the wave
    const int fr = lane & 15, fq = lane >> 4;

    const int sr = tid >> 3;                      // 0..63 local row
    const int sc = ((tid & 7) ^ (sr & 7)) * 8;    // inverse-swizzled source col
    auto stage_unit = [&](int t, int u) {         // u0-3: A rows; u4-6: B gate rows
        const unsigned short* src = (u < 4)
            ? A + (size_t)(bm + u * 64 + sr) * K + t * 64 + sc
            : W + (size_t)((u - 4) * 1024 + hbase + sr) * K + t * 64 + sc;
        char* dst = ldsb + (t & 1) * 57344 + ((u < 4) ? u * 8192 : 32768 + (u - 4) * 8192)
                    + tid * 16;
        __builtin_amdgcn_global_load_lds(
            (const __attribute__((address_space(1))) void*)src,
            (__attribute__((address_space(3))) void*)dst, 16, 0, 0);
    };

    f32x4 acc[8][3];
#pragma unroll
    for (int i = 0; i < 8; i++)
#pragma unroll
        for (int j = 0; j < 3; j++) acc[i][j] = (f32x4){0.f, 0.f, 0.f, 0.f};
    bf16x8 a[4], b0[3], b1[3];

    const int nt = K >> 6;   // 16

    // prologue: tile0 all 7 units + tile1 {u0,u2,u4,u5,u6}; vmcnt(5) = tile0 done
#pragma unroll
    for (int u = 0; u < 7; ++u) stage_unit(0, u);
    stage_unit(1, 0); stage_unit(1, 2);
    stage_unit(1, 4); stage_unit(1, 5); stage_unit(1, 6);
    asm volatile("s_waitcnt vmcnt(5)" ::: "memory");
    __builtin_amdgcn_sched_barrier(0);
    __builtin_amdgcn_s_barrier();

#define RDA_G(BUF, MH, KQ)                                                         \
    _Pragma("unroll")                                                              \
    for (int m_ = 0; m_ < 4; ++m_)                                                 \
        a[m_] = *reinterpret_cast<const bf16x8*>(                                  \
            ldsb + (BUF) * 57344 + (gm * 128 + (MH) * 64 + m_ * 16 + fr) * 128 +   \
            (((KQ) * 4 + fq) ^ (fr & 7)) * 16);
#define RDB_G(BUF, KQ, DST)                                                        \
    _Pragma("unroll")                                                              \
    for (int n_ = 0; n_ < 3; ++n_)                                                 \
        DST[n_] = *reinterpret_cast<const bf16x8*>(                                \
            ldsb + (BUF) * 57344 + 32768 + (n_ * 64 + hb + fr) * 128 +             \
            (((KQ) * 4 + fq) ^ (fr & 7)) * 16);
#define MM_G(MH, BV)                                                               \
    __builtin_amdgcn_s_setprio(1);                                                 \
    _Pragma("unroll")                                                              \
    for (int m_ = 0; m_ < 4; ++m_)                                                 \
        _Pragma("unroll")                                                          \
        for (int n_ = 0; n_ < 3; ++n_)                                             \
            acc[(MH) * 4 + m_][n_] = __builtin_amdgcn_mfma_f32_16x16x32_bf16(      \
                a[m_], BV[n_], acc[(MH) * 4 + m_][n_], 0, 0, 0);                   \
    __builtin_amdgcn_s_setprio(0);

    for (int t = 0; t < nt; ++t) {
        const int buf = t & 1;
        RDB_G(buf, 0, b0); RDA_G(buf, 0, 0);
        if (t + 1 < nt) stage_unit(t + 1, 1);
        MM_G(0, b0); __builtin_amdgcn_s_barrier();
        RDB_G(buf, 1, b1); RDA_G(buf, 0, 1);
        if (t + 1 < nt) stage_unit(t + 1, 3);
        MM_G(0, b1); __builtin_amdgcn_s_barrier();
        RDA_G(buf, 1, 0);
        if (t + 2 < nt) { stage_unit(t + 2, 0); stage_unit(t + 2, 2); }
        MM_G(1, b0); __builtin_amdgcn_s_barrier();
        RDA_G(buf, 1, 1);
        if (t + 2 < nt) { stage_unit(t + 2, 4); stage_unit(t + 2, 5); stage_unit(t + 2, 6); }
        MM_G(1, b1);
        if (t + 2 < nt) {
            asm volatile("s_waitcnt vmcnt(5)" ::: "memory");
            __builtin_amdgcn_sched_barrier(0);
        } else if (t + 1 < nt) {
            asm volatile("s_waitcnt vmcnt(0)" ::: "memory");
            __builtin_amdgcn_sched_barrier(0);
        }
        __builtin_amdgcn_s_barrier();
    }
#undef RDA_G
#undef RDB_G
#undef MM_G

    // epilogue: GRU step-3 combine in-register -> clauseb (col h, rows per frag)
    const int h = hbase + hb + fr;
    const float br = bias[h], bz = bias[1024 + h], bn = bias[2048 + h];
#pragma unroll
    for (int mi = 0; mi < 8; ++mi) {
#pragma unroll
        for (int jj = 0; jj < 4; ++jj) {
            const int row = bm + gm * 128 + (mi >> 2) * 64 + (mi & 3) * 16 + fq * 4 + jj;
            const int t2 = toks[row * 3 + 2];
            const float* gi = Gi + (size_t)t2 * H3;
            const float gh2r = acc[mi][0][jj] + br;
            const float gh2z = acc[mi][1][jj] + bz;
            const float gh2n = acc[mi][2][jj] + bn;
            const float r = sigf(gi[h] + gh2r);
            const float z = sigf(gi[1024 + h] + gh2z);
            const float n = tanhf(fmaf(r, gh2n, gi[2048 + h]));
            const float hv = bf2f(A[(size_t)row * 1024 + h]);   // h2 value (A == h2b)
            outb[(size_t)row * 1024 + h] = f2bf((1.f - z) * n + z * hv);
        }
    }
}

// ============ 128x256-tile, 3-buffer, 2-phase counted-vmcnt GEMM (K9/K10) ======
template<bool RELU, int OUT_MODE>   // 1: bf16 C (+bias,RELU); 2: fused w3 dot
__global__ __launch_bounds__(512, 2)
void gemm_n(const unsigned short* __restrict__ A, const unsigned short* __restrict__ W,
            const float* __restrict__ bias, void* __restrict__ C,
            int N, int K, int gx,
            const float* __restrict__ w3, float* __restrict__ logits)
{
    __shared__ unsigned short lds[73728];   // 144 KiB
    char* ldsb = (char*)lds;
    const int tid = threadIdx.x;
    const int wid = tid >> 6, lane = tid & 63;

    const int nwg = gridDim.x;
    const int cpx = nwg >> 3;
    const int bid = blockIdx.x;
    const int swz = (bid & 7) * cpx + (bid >> 3);
    const int bm = (swz / gx) * 128;
    const int bn = (swz % gx) * 256;

    const int g = wid >> 2;
    const int wn = (wid & 3) * 64;
    const int fr = lane & 15, fq = lane >> 4;

    const int sr = tid >> 3;
    const int sc = ((tid & 7) ^ (sr & 7)) * 8;
    auto stage_unit = [&](int t, int u) {
        const unsigned short* src = (u < 2)
            ? A + (size_t)(bm + u * 64 + sr) * K + t * 64 + sc
            : W + (size_t)(bn + (u - 2) * 64 + sr) * K + t * 64 + sc;
        char* dst = ldsb + (t % 3) * 49152 + u * 8192 + tid * 16;
        __builtin_amdgcn_global_load_lds(
            (const __attribute__((address_space(1))) void*)src,
            (__attribute__((address_space(3))) void*)dst, 16, 0, 0);
    };

    f32x4 acc[4][4];
#pragma unroll
    for (int i = 0; i < 4; i++)
#pragma unroll
        for (int j = 0; j < 4; j++) acc[i][j] = (f32x4){0.f, 0.f, 0.f, 0.f};
    bf16x8 a[4], b[4];

    const int nt = K >> 6;

#pragma unroll
    for (int u = 0; u < 6; ++u) stage_unit(0, u);
#pragma unroll
    for (int u = 0; u < 6; ++u) stage_unit(1, u);
    asm volatile("s_waitcnt vmcnt(6)" ::: "memory");
    __builtin_amdgcn_sched_barrier(0);
    __builtin_amdgcn_s_barrier();

    for (int t = 0; t < nt; ++t) {
        const int buf = (t % 3) * 49152;
#pragma unroll
        for (int n_ = 0; n_ < 4; ++n_)
            b[n_] = *reinterpret_cast<const bf16x8*>(
                ldsb + buf + 16384 + (wn + n_ * 16 + fr) * 128 + ((fq) ^ (fr & 7)) * 16);
#pragma unroll
        for (int m_ = 0; m_ < 4; ++m_)
            a[m_] = *reinterpret_cast<const bf16x8*>(
                ldsb + buf + (g * 64 + m_ * 16 + fr) * 128 + ((fq) ^ (fr & 7)) * 16);
        if (t + 2 < nt) { stage_unit(t + 2, 0); stage_unit(t + 2, 1); stage_unit(t + 2, 2); }
        __builtin_amdgcn_s_setprio(1);
#pragma unroll
        for (int m_ = 0; m_ < 4; ++m_)
#pragma unroll
            for (int n_ = 0; n_ < 4; ++n_)
                acc[m_][n_] = __builtin_amdgcn_mfma_f32_16x16x32_bf16(a[m_], b[n_], acc[m_][n_], 0, 0, 0);
        __builtin_amdgcn_s_setprio(0);
        __builtin_amdgcn_s_barrier();
#pragma unroll
        for (int n_ = 0; n_ < 4; ++n_)
            b[n_] = *reinterpret_cast<const bf16x8*>(
                ldsb + buf + 16384 + (wn + n_ * 16 + fr) * 128 + ((4 + fq) ^ (fr & 7)) * 16);
#pragma unroll
        for (int m_ = 0; m_ < 4; ++m_)
            a[m_] = *reinterpret_cast<const bf16x8*>(
                ldsb + buf + (g * 64 + m_ * 16 + fr) * 128 + ((4 + fq) ^ (fr & 7)) * 16);
        if (t + 2 < nt) { stage_unit(t + 2, 3); stage_unit(t + 2, 4); stage_unit(t + 2, 5); }
        __builtin_amdgcn_s_setprio(1);
#pragma unroll
        for (int m_ = 0; m_ < 4; ++m_)
#pragma unroll
            for (int n_ = 0; n_ < 4; ++n_)
                acc[m_][n_] = __builtin_amdgcn_mfma_f32_16x16x32_bf16(a[m_], b[n_], acc[m_][n_], 0, 0, 0);
        __builtin_amdgcn_s_setprio(0);
        if (t + 2 < nt) {
            asm volatile("s_waitcnt vmcnt(6)" ::: "memory");
            __builtin_amdgcn_sched_barrier(0);
        } else if (t + 1 < nt) {
            asm volatile("s_waitcnt vmcnt(0)" ::: "memory");
            __builtin_amdgcn_sched_barrier(0);
        }
        __builtin_amdgcn_s_barrier();
    }

    if (OUT_MODE == 2) {
        float rs[4][4];
#pragma unroll
        for (int m = 0; m < 4; m++)
#pragma unroll
            for (int j = 0; j < 4; j++) rs[m][j] = 0.f;
#pragma unroll
        for (int n = 0; n < 4; n++) {
            const int col = bn + wn + n * 16 + fr;
            const float bv = bias[col];
            const float wv = w3[col];
#pragma unroll
            for (int m = 0; m < 4; m++)
#pragma unroll
                for (int j = 0; j < 4; j++) {
                    float v = acc[m][n][j] + bv;
                    if (RELU) v = fmaxf(v, 0.f);
                    rs[m][j] = fmaf(v, wv, rs[m][j]);
                }
        }
#pragma unroll
        for (int m = 0; m < 4; m++)
#pragma unroll
            for (int j = 0; j < 4; j++) {
                float s = rs[m][j];
                s += __shfl_xor(s, 1); s += __shfl_xor(s, 2);
                s += __shfl_xor(s, 4); s += __shfl_xor(s, 8);
                if (fr == 0) atomicAdd(logits + bm + g * 64 + m * 16 + fq * 4 + j, s);
            }
    } else {
#pragma unroll
        for (int m = 0; m < 4; m++) {
#pragma unroll
            for (int n = 0; n < 4; n++) {
                const int col = bn + wn + n * 16 + fr;
                const float bv = bias[col];
#pragma unroll
                for (int j = 0; j < 4; j++) {
                    const int row = bm + g * 64 + m * 16 + fq * 4 + j;
                    float v = acc[m][n][j] + bv;
                    if (RELU) v = fmaxf(v, 0.f);
                    ((unsigned short*)C)[(size_t)row * N + col] = f2bf(v);
                }
            }
        }
    }
}

// ============ 128x128 ring GEMM (small/split-K matrices) ============
template<bool RELU, int OUT_MODE>   // 3 = fp32 atomicAdd (split-K)
__global__ __launch_bounds__(256)
void gemm_bf16(const unsigned short* __restrict__ A, const unsigned short* __restrict__ W,
               const float* __restrict__ bias, void* __restrict__ C,
               int N, int K, int gx, int Kc,
               const float* __restrict__ w3, float* __restrict__ logits)
{
    __shared__ unsigned short As[4][128 * 32];
    __shared__ unsigned short Ws[4][128 * 32];
    const int tid = threadIdx.x;
    const int wid = tid >> 6, lane = tid & 63;

    const int nwg = gridDim.x;
    const int cpx = nwg >> 3;
    const int bid = blockIdx.x;
    const int swz = (bid & 7) * cpx + (bid >> 3);
    const int bm = (swz / gx) * 128;
    const int bn = (swz % gx) * 128;
    const int k_base = blockIdx.y * Kc;
    const int nt = Kc >> 5;

    const int wm = (wid >> 1) * 64, wn = (wid & 1) * 64;
    const int fr = lane & 15;
    const int fq = lane >> 4;
    const int perm = fq ^ (fr & 3);

    f32x4 acc[4][4];
#pragma unroll
    for (int i = 0; i < 4; i++)
#pragma unroll
        for (int j = 0; j < 4; j++) acc[i][j] = (f32x4){0.f, 0.f, 0.f, 0.f};

    const int srow = tid >> 2;
    const int schunk = (tid & 3) ^ (srow & 3);
    const unsigned short* aS = A + (size_t)(bm + srow) * K + k_base + schunk * 8;
    const unsigned short* wS = W + (size_t)(bn + srow) * K + k_base + schunk * 8;
    const size_t rstep = (size_t)64 * K;

    auto stage = [&](int b, int t) {
        const unsigned short* a0 = aS + t * 32;
        const unsigned short* w0 = wS + t * 32;
        __builtin_amdgcn_global_load_lds(
            (const __attribute__((address_space(1))) void*)a0,
            (__attribute__((address_space(3))) void*)(&As[b][wid * 512]), 16, 0, 0);
        __builtin_amdgcn_global_load_lds(
            (const __attribute__((address_space(1))) void*)(a0 + rstep),
            (__attribute__((address_space(3))) void*)(&As[b][2048 + wid * 512]), 16, 0, 0);
        __builtin_amdgcn_global_load_lds(
            (const __attribute__((address_space(1))) void*)w0,
            (__attribute__((address_space(3))) void*)(&Ws[b][wid * 512]), 16, 0, 0);
        __builtin_amdgcn_global_load_lds(
            (const __attribute__((address_space(1))) void*)(w0 + rstep),
            (__attribute__((address_space(3))) void*)(&Ws[b][2048 + wid * 512]), 16, 0, 0);
    };

    stage(0, 0);
    if (nt > 1) stage(1, 1);
    if (nt > 2) stage(2, 2);

    for (int t = 0; t < nt; ++t) {
        if (t + 2 < nt)      asm volatile("s_waitcnt vmcnt(8)" ::: "memory");
        else if (t + 1 < nt) asm volatile("s_waitcnt vmcnt(4)" ::: "memory");
        else                 asm volatile("s_waitcnt vmcnt(0)" ::: "memory");
        __builtin_amdgcn_s_barrier();
        __builtin_amdgcn_sched_barrier(0);
        if (t + 3 < nt) stage((t + 3) & 3, t + 3);

        const unsigned short* as = &As[t & 3][0];
        const unsigned short* ws = &Ws[t & 3][0];
        bf16x8 a[4], b[4];
#pragma unroll
        for (int m = 0; m < 4; m++)
            a[m] = *reinterpret_cast<const bf16x8*>(as + (wm + m * 16 + fr) * 32 + perm * 8);
#pragma unroll
        for (int n = 0; n < 4; n++)
            b[n] = *reinterpret_cast<const bf16x8*>(ws + (wn + n * 16 + fr) * 32 + perm * 8);
        __builtin_amdgcn_s_setprio(1);
#pragma unroll
        for (int m = 0; m < 4; m++)
#pragma unroll
            for (int n = 0; n < 4; n++)
                acc[m][n] = __builtin_amdgcn_mfma_f32_16x16x32_bf16(a[m], b[n], acc[m][n], 0, 0, 0);
        __builtin_amdgcn_s_setprio(0);
    }

    if (OUT_MODE == 3) {
        float* Cf = (float*)C;
#pragma unroll
        for (int m = 0; m < 4; m++)
#pragma unroll
            for (int n = 0; n < 4; n++) {
                const int col = bn + wn + n * 16 + fr;
#pragma unroll
                for (int j = 0; j < 4; j++) {
                    const int row = bm + wm + m * 16 + fq * 4 + j;
                    atomicAdd(Cf + (size_t)row * N + col, acc[m][n][j]);
                }
            }
    } else {
#pragma unroll
        for (int m = 0; m < 4; m++) {
#pragma unroll
            for (int n = 0; n < 4; n++) {
                const int col = bn + wn + n * 16 + fr;
                const float bv = bias[col];
#pragma unroll
                for (int j = 0; j < 4; j++) {
                    const int row = bm + wm + m * 16 + fq * 4 + j;
                    float v = acc[m][n][j] + bv;
                    if (RELU) v = fmaxf(v, 0.f);
                    if (OUT_MODE == 1)
                        ((unsigned short*)C)[(size_t)row * N + col] = f2bf(v);
                    else
                        ((float*)C)[(size_t)row * N + col] = v;
                }
            }
        }
    }
}

// ========= prep: all weight cvt + gh0 gemv (fused with W_hh read) + prefill =====
__global__ __launch_bounds__(256)
void prep(const float* __restrict__ W_hh, const float* __restrict__ W_ih,
          const float* __restrict__ W1, const float* __restrict__ W2,
          const float* __restrict__ W_emb, const float* __restrict__ table,
          const float* __restrict__ state, const float* __restrict__ b_emb,
          const float* __restrict__ b_ih, const float* __restrict__ b_hh,
          unsigned short* __restrict__ W_hhb, unsigned short* __restrict__ W_ihb,
          unsigned short* __restrict__ W1b, unsigned short* __restrict__ W2b,
          unsigned short* __restrict__ W_embb, unsigned short* __restrict__ tableb,
          float* __restrict__ gh0, float* __restrict__ emb32, float* __restrict__ Gi,
          float* __restrict__ gh1, float* __restrict__ logits)
{
    int b = blockIdx.x;
    const int t = threadIdx.x;
    if (b < 3072) {   // W_hh row b: convert + fused gemv
        float4 w = *reinterpret_cast<const float4*>(W_hh + (size_t)b * H + t * 4);
        ushort4 o; o.x = f2bf(w.x); o.y = f2bf(w.y); o.z = f2bf(w.z); o.w = f2bf(w.w);
        *reinterpret_cast<ushort4*>(W_hhb + (size_t)b * H + t * 4) = o;
        float4 sv = *reinterpret_cast<const float4*>(state + t * 4);
        float s = w.x * sv.x + w.y * sv.y + w.z * sv.z + w.w * sv.w;
#pragma unroll
        for (int off = 32; off; off >>= 1) s += __shfl_down(s, off);
        __shared__ float ps[4];
        if ((t & 63) == 0) ps[t >> 6] = s;
        __syncthreads();
        if (t == 0) gh0[b] = ps[0] + ps[1] + ps[2] + ps[3] + b_hh[b];
        return;
    }
    b -= 3072;
    const float* src = nullptr; unsigned short* dst = nullptr;
    if (b < 3072)      { src = W_ih;  dst = W_ihb; }
    else if ((b -= 3072) < 1024) { src = W1; dst = W1b; }
    else if ((b -= 1024) < 1024) { src = W2; dst = W2b; }
    else if ((b -= 1024) < 1024) { src = W_emb; dst = W_embb; }
    else if ((b -= 1024) < 256)  { src = table; dst = tableb; }
    else {
        b -= 256;
        if (b < 256) {
            int i = b * 1024 + t * 4;
            *reinterpret_cast<float4*>(emb32 + i) =
                *reinterpret_cast<const float4*>(b_emb + (i & (H - 1)));
        } else if ((b -= 256) < 768) {
            int i = b * 1024 + t * 4;
            *reinterpret_cast<float4*>(Gi + i) =
                *reinterpret_cast<const float4*>(b_ih + i % H3);
        } else if ((b -= 768) < 768) {
            int i = b * 1024 + t * 4;
            *reinterpret_cast<float4*>(gh1 + i) =
                *reinterpret_cast<const float4*>(b_hh + i % H3);
        } else {
            b -= 768;
            int i = b * 1024 + t * 4;
            *reinterpret_cast<float4*>(logits + i) = (float4){0.f, 0.f, 0.f, 0.f};
        }
        return;
    }
    const int off = b * 1024 + t * 4;
    float4 v = *reinterpret_cast<const float4*>(src + off);
    ushort4 o; o.x = f2bf(v.x); o.y = f2bf(v.y); o.z = f2bf(v.z); o.w = f2bf(v.w);
    *reinterpret_cast<ushort4*>(dst + off) = o;
}

// ---------------- fp32 -> bf16 (emb) ----------------
__global__ void cvt_emb(const float* __restrict__ in, unsigned short* __restrict__ out)
{
    int i = (blockIdx.x * blockDim.x + threadIdx.x) * 4;
    float4 v = *reinterpret_cast<const float4*>(in + i);
    ushort4 o;
    o.x = f2bf(v.x); o.y = f2bf(v.y); o.z = f2bf(v.z); o.w = f2bf(v.w);
    *reinterpret_cast<ushort4*>(out + i) = o;
}

// ---------------- GRU combine kernels ----------------
__global__ void h1_combine(const float* __restrict__ Gi, const float* __restrict__ gh0,
                           const float* __restrict__ state, float* __restrict__ h1,
                           unsigned short* __restrict__ h1b)
{
    int idx = blockIdx.x * blockDim.x + threadIdx.x;
    int v = idx >> 10, h = idx & (H - 1);
    const float* g = Gi + (size_t)v * H3;
    float r = sigf(g[h] + gh0[h]);
    float z = sigf(g[H + h] + gh0[H + h]);
    float n = tanhf(fmaf(r, gh0[2 * H + h], g[2 * H + h]));
    float v2 = (1.f - z) * n + z * state[h];
    h1[idx] = v2;
    h1b[idx] = f2bf(v2);
}

__global__ void step2_both(const int* __restrict__ rel, const int* __restrict__ attr, int Nr,
                           const float* __restrict__ Gi, const float* __restrict__ gh1,
                           const float* __restrict__ h1,
                           unsigned short* __restrict__ h2b, unsigned short* __restrict__ attr_out)
{
    int idx = blockIdx.x * blockDim.x + threadIdx.x;
    int row = idx >> 10, h = idx & (H - 1);
    int t0, t1, orow = row;
    unsigned short* dst;
    if (row < Nr) { t0 = rel[row * 3 + 0]; t1 = rel[row * 3 + 1]; dst = h2b; }
    else { orow = row - Nr; t0 = attr[orow * 2 + 0]; t1 = attr[orow * 2 + 1]; dst = attr_out; }
    const float* g = Gi + (size_t)t1 * H3;
    const float* gh = gh1 + (size_t)t0 * H3;
    float r = sigf(g[h] + gh[h]);
    float z = sigf(g[H + h] + gh[H + h]);
    float n = tanhf(fmaf(r, gh[2 * H + h], g[2 * H + h]));
    float v = (1.f - z) * n + z * h1[(size_t)t0 * H + h];
    dst[(size_t)orow * H + h] = f2bf(v);
}

// ---------------- softmax + eps smoothing ----------------
__global__ void softmax_eps(const float* __restrict__ logits, const float* __restrict__ epsp,
                            float* __restrict__ out, int N)
{
    __shared__ float smax[16], ssum[16];
    int tid = threadIdx.x;
    int nw = blockDim.x >> 6;
    float m = -INFINITY;
    for (int i = tid; i < N; i += blockDim.x) m = fmaxf(m, logits[i]);
#pragma unroll
    for (int off = 32; off; off >>= 1) m = fmaxf(m, __shfl_down(m, off));
    if ((tid & 63) == 0) smax[tid >> 6] = m;
    __syncthreads();
    float M = smax[0];
    for (int i = 1; i < nw; i++) M = fmaxf(M, smax[i]);
    float s = 0.f;
    for (int i = tid; i < N; i += blockDim.x) s += expf(logits[i] - M);
#pragma unroll
    for (int off = 32; off; off >>= 1) s += __shfl_down(s, off);
    if ((tid & 63) == 0) ssum[tid >> 6] = s;
    __syncthreads();
    float S = 0.f;
    for (int i = 0; i < nw; i++) S += ssum[i];
    float e = epsp[0];
    float mul = (1.f - e) / S;
    float add = e / (float)N;
    for (int i = tid; i < N; i += blockDim.x) out[i] = expf(logits[i] - M) * mul + add;
}

extern "C" void kernel_launch(void* const* d_in, const int* in_sizes, int n_in,
                              void* d_out, int out_size, void* d_ws, size_t ws_size,
                              hipStream_t stream)
{
    const float* state       = (const float*)d_in[0];
    const int*   rel_tokens  = (const int*)d_in[1];
    const int*   attr_tokens = (const int*)d_in[2];
    const float* table       = (const float*)d_in[3];
    const float* W_emb       = (const float*)d_in[4];
    const float* b_emb       = (const float*)d_in[5];
    const float* W_ih        = (const float*)d_in[6];
    const float* W_hh        = (const float*)d_in[7];
    const float* b_ih        = (const float*)d_in[8];
    const float* b_hh        = (const float*)d_in[9];
    const float* W1          = (const float*)d_in[10];
    const float* b1          = (const float*)d_in[11];
    const float* W2          = (const float*)d_in[12];
    const float* b2          = (const float*)d_in[13];
    const float* W3          = (const float*)d_in[14];
    const float* eps         = (const float*)d_in[16];

    const int Nr = in_sizes[1] / 3;   // 4096
    const int Na = in_sizes[2] / 2;   // 4096
    const int Ntot = Nr + Na;         // 8192

    float* ws     = (float*)d_ws;
    float* Gi     = ws;
    float* gh0    = Gi + NVOC * H3;
    float* h1     = gh0 + H3;
    float* gh1    = h1 + NVOC * H;
    float* emb32  = gh1 + NVOC * H3;
    float* logits = emb32 + NVOC * H;
    unsigned short* W_hhb   = (unsigned short*)(logits + Ntot);
    unsigned short* W_ihb   = W_hhb + (size_t)H3 * H;
    unsigned short* W1b     = W_ihb + (size_t)H3 * H;
    unsigned short* W2b     = W1b + (size_t)H * H;
    unsigned short* W_embb  = W2b + (size_t)H * H;
    unsigned short* tableb  = W_embb + (size_t)H * H;
    unsigned short* embb    = tableb + (size_t)NVOC * H;
    unsigned short* h1b     = embb + (size_t)NVOC * H;
    unsigned short* h2b     = h1b + (size_t)NVOC * H;
    unsigned short* clauseb = h2b + (size_t)Nr * H;
    unsigned short* x1b     = clauseb + (size_t)Ntot * H;

    // P0: all weight cvt + gh0 gemv + bias prefills + logits zero
    prep<<<11272, 256, 0, stream>>>(W_hh, W_ih, W1, W2, W_emb, table, state,
                                    b_emb, b_ih, b_hh,
                                    W_hhb, W_ihb, W1b, W2b, W_embb, tableb,
                                    gh0, emb32, Gi, gh1, logits);

    // K1: emb32 += table @ W_emb^T  (split-K=4)                   [256,1024]
    gemm_bf16<false, 3><<<dim3((H / 128) * (NVOC / 128), 4), 256, 0, stream>>>(
        tableb, W_embb, nullptr, emb32, H, H, H / 128, H / 4, nullptr, nullptr);
    cvt_emb<<<NVOC * H / 4 / 256, 256, 0, stream>>>(emb32, embb);
    // K2: Gi += emb @ W_ih^T  (split-K=4)                         [256,3072]
    gemm_bf16<false, 3><<<dim3((H3 / 128) * (NVOC / 128), 4), 256, 0, stream>>>(
        embb, W_ihb, nullptr, Gi, H3, H, H3 / 128, H / 4, nullptr, nullptr);
    // K4: h1[v] for the 256 distinct tokens
    h1_combine<<<NVOC * H / 256, 256, 0, stream>>>(Gi, gh0, state, h1, h1b);
    // K5: gh1 += h1 @ W_hh^T  (split-K=4)                         [256,3072]
    gemm_bf16<false, 3><<<dim3((H3 / 128) * (NVOC / 128), 4), 256, 0, stream>>>(
        h1b, W_hhb, nullptr, gh1, H3, H, H3 / 128, H / 4, nullptr, nullptr);
    // K6: step 2 both branches -> h2b + clauseb[Nr:]
    step2_both<<<Ntot * (H / 256), 256, 0, stream>>>(rel_tokens, attr_tokens, Nr,
                                                     Gi, gh1, h1, h2b,
                                                     clauseb + (size_t)Nr * H);
    // K7+K8 fused: clauseb[0:Nr] = GRU3(h2 @ W_hh^T + b_hh)  [4096x(3x64)] x16x16
    gemm_gru<<<16 * 16, 512, 0, stream>>>(h2b, W_hhb, b_hh, Gi, rel_tokens,
                                          clauseb, H, H / 64);
    // K9: x1b = relu(clause @ W1^T + b1)   [8192,1024]  gemm_n (256 blocks)
    gemm_n<true, 1><<<(Ntot / 128) * (H / 256), 512, 0, stream>>>(
        clauseb, W1b, b1, x1b, H, H, H / 256, nullptr, nullptr);
    // K10+K11: logits += relu(x1 @ W2^T + b2) . W3   [8192]  gemm_n (256 blocks)
    gemm_n<true, 2><<<(Ntot / 128) * (H / 256), 512, 0, stream>>>(
        x1b, W2b, b2, nullptr, H, H, H / 256, W3, logits);
    // K12: softmax + eps smoothing -> d_out
    softmax_eps<<<1, 1024, 0, stream>>>(logits, eps, (float*)d_out, Ntot);
}